// Round 4
// baseline (1286.258 us; speedup 1.0000x reference)
//
#include <hip/hip_runtime.h>

#define N1V 100000
#define N2V 500
#define NEV 1000000
#define ALPHAV 0.2f
#define NGRP (NEV / 64)        // 15625 edge-groups
#define EGB 2048               // k_edge blocks
#define EG_WAVES (EGB * 4)

__device__ __forceinline__ float wave_sum(float v) {
#pragma unroll
  for (int off = 32; off > 0; off >>= 1) v += __shfl_xor(v, off, 64);
  return v;
}

// ---------------- prep: c[320] = a^T @ a_2 ; aT[p*128+j] = a[j*320+p] ----------------
__global__ __launch_bounds__(256) void k_prep(const float* __restrict__ a,
                                              const float* __restrict__ a2,
                                              float* __restrict__ c,
                                              float* __restrict__ aT) {
  int b = blockIdx.x;
  if (b < 160) {
    int id = b * 256 + threadIdx.x;          // 0..40959
    int p = id >> 7, j = id & 127;
    aT[id] = a[j * 320 + p];
  } else {
    int p = (b - 160) * 256 + threadIdx.x;   // 0..511
    if (p < 320) {
      float s = 0.f;
      for (int k = 0; k < 128; ++k) s += a2[k] * a[k * 320 + p];
      c[p] = s;
    }
  }
}

// ---------------- z2[t] = x2[t].c2 ; z1[i] = x1[i].c1 ----------------
__global__ __launch_bounds__(256) void k_z2(const float* __restrict__ x2,
                                            const float* __restrict__ c,
                                            float* __restrict__ z2g) {
  int w = (blockIdx.x * 256 + threadIdx.x) >> 6;
  int l = threadIdx.x & 63;
  if (w >= N2V) return;
  float p = x2[w * 128 + l] * c[128 + l] + x2[w * 128 + 64 + l] * c[192 + l];
  float s = wave_sum(p);
  if (l == 0) z2g[w] = s;
}

__global__ __launch_bounds__(256) void k_z1(const float* __restrict__ x1,
                                            const float* __restrict__ c,
                                            float* __restrict__ z1g) {
  int w = (blockIdx.x * 256 + threadIdx.x) >> 6;
  int l = threadIdx.x & 63;
  if (w >= N1V) return;
  float p = x1[w * 128 + l] * c[l] + x1[w * 128 + 64 + l] * c[64 + l];
  float s = wave_sum(p);
  if (l == 0) z1g[w] = s;
}

// ---------------- src histogram ----------------
__global__ __launch_bounds__(256) void k_hist(const int* __restrict__ src,
                                              int* __restrict__ c1) {
  for (int e = blockIdx.x * blockDim.x + threadIdx.x; e < NEV; e += gridDim.x * blockDim.x)
    atomicAdd(&c1[src[e]], 1);
}

// ---------------- scan for src counts ----------------
__global__ __launch_bounds__(256) void k_scanA(const int* __restrict__ cnt,
                                               int* __restrict__ outp,
                                               int* __restrict__ partials, int n) {
  __shared__ int s[256];
  int tid = threadIdx.x;
  int base = blockIdx.x * 2048 + tid * 8;
  int v[8]; int tot = 0;
#pragma unroll
  for (int j = 0; j < 8; ++j) { int idx = base + j; v[j] = (idx < n) ? cnt[idx] : 0; tot += v[j]; }
  s[tid] = tot; __syncthreads();
  for (int off = 1; off < 256; off <<= 1) {
    int tv = 0;
    if (tid >= off) tv = s[tid - off];
    __syncthreads();
    if (tid >= off) s[tid] += tv;
    __syncthreads();
  }
  int run = s[tid] - tot;
#pragma unroll
  for (int j = 0; j < 8; ++j) { int idx = base + j; if (idx < n) outp[idx] = run; run += v[j]; }
  if (tid == 255) partials[blockIdx.x] = s[255];
}

__global__ __launch_bounds__(64) void k_scanP(int* __restrict__ partials, int nPart) {
  if (threadIdx.x == 0) {
    int run = 0;
    for (int b = 0; b < nPart; ++b) { int t = partials[b]; partials[b] = run; run += t; }
  }
}

__global__ __launch_bounds__(256) void k_scanC(int* __restrict__ rp, int* __restrict__ cur,
                                               const int* __restrict__ partials, int n, int total) {
  int i = blockIdx.x * 256 + threadIdx.x;
  if (i < n) {
    int v = rp[i] + partials[i >> 11];
    rp[i] = v; cur[i] = v;
  }
  if (i == 0) rp[n] = total;
}

// ---------------- src scatter into CSR ----------------
__global__ __launch_bounds__(256) void k_scatter(const int* __restrict__ src,
                                                 int* __restrict__ cur1,
                                                 int* __restrict__ e1) {
  for (int e = blockIdx.x * blockDim.x + threadIdx.x; e < NEV; e += gridDim.x * blockDim.x) {
    int p = atomicAdd(&cur1[src[e]], 1);
    e1[p] = e;
  }
}

// ---------------- fused linear edge pass: wave per 64-edge group ----------------
// computes w -> wbuf (coalesced); accumulates ALL dst-side sums via x8-replicated
// global atomics: gee[rep][512][64] (w*ee), gx1[rep][512][128] (w*x1[src]),
// rs2rep[rep][512] (w).
__global__ __launch_bounds__(256) void k_edge(const float* __restrict__ ee,
                                              const int* __restrict__ src,
                                              const int* __restrict__ dst,
                                              const float* __restrict__ x1,
                                              const float* __restrict__ z1g,
                                              const float* __restrict__ z2g,
                                              const float* __restrict__ c,
                                              float* __restrict__ wbuf,
                                              float* __restrict__ gee,
                                              float* __restrict__ gx1,
                                              float* __restrict__ rs2rep) {
  int l = threadIdx.x & 63;
  int wid = (blockIdx.x * 256 + threadIdx.x) >> 6;
  int rep = blockIdx.x & 7;
  float c3l = c[256 + l];
  float* geeR = gee + (size_t)rep * 512 * 64;
  float* gx1R = gx1 + (size_t)rep * 512 * 128;
  float* rsR = rs2rep + rep * 512;

  for (int g = wid; g < NGRP; g += EG_WAVES) {
    int e = g * 64 + l;
    int sv = src[e], dv = dst[e];
    float zpre = z1g[sv] + z2g[dv];
    size_t base = (size_t)g * 64 * 64;
    // prefetch j=0
    float ev = ee[base + l];
    int sj = __shfl(sv, 0);
    float ya = x1[(size_t)sj * 128 + l];
    float yb = x1[(size_t)sj * 128 + 64 + l];
    float wloc = 0.f;
    for (int j = 0; j < 64; ++j) {
      float evn = 0.f, yan = 0.f, ybn = 0.f;
      if (j < 63) {
        evn = ee[base + (size_t)(j + 1) * 64 + l];
        int sjn = __shfl(sv, j + 1);
        yan = x1[(size_t)sjn * 128 + l];
        ybn = x1[(size_t)sjn * 128 + 64 + l];
      }
      float z3 = wave_sum(ev * c3l);
      float z = __shfl(zpre, j) + z3;
      float zp = z > 0.f ? z : ALPHAV * z;
      float w = __expf(-zp);
      if (l == j) wloc = w;
      int dj = __shfl(dv, j);
      atomicAdd(&geeR[dj * 64 + l], w * ev);
      atomicAdd(&gx1R[dj * 128 + l], w * ya);
      atomicAdd(&gx1R[dj * 128 + 64 + l], w * yb);
      ev = evn; ya = yan; yb = ybn;
    }
    wbuf[e] = wloc;
    atomicAdd(&rsR[dv], wloc);
  }
}

// ---------------- src gather pass: 4-wide pipelined gather+FMA ----------------
__global__ __launch_bounds__(256) void k_src(const float* __restrict__ x2,
                                             const float* __restrict__ ee,
                                             const int* __restrict__ edge_dst,
                                             const int* __restrict__ rp1,
                                             const int* __restrict__ eidx,
                                             const float* __restrict__ wbuf,
                                             float* __restrict__ sbuf1,
                                             float* __restrict__ rs1) {
  int wid = (blockIdx.x * 256 + threadIdx.x) >> 6;
  int l = threadIdx.x & 63;
  if (wid >= N1V) return;
  int start = rp1[wid], end = rp1[wid + 1];
  float s2a = 0.f, s2b = 0.f, s1 = 0.f, rsum = 0.f;
  int p = start;
  for (; p + 4 <= end; p += 4) {
    int e0 = eidx[p], e1 = eidx[p + 1], e2 = eidx[p + 2], e3 = eidx[p + 3];
    float w0 = wbuf[e0], w1 = wbuf[e1], w2 = wbuf[e2], w3 = wbuf[e3];
    int d0 = edge_dst[e0], d1 = edge_dst[e1], d2 = edge_dst[e2], d3 = edge_dst[e3];
    float ev0 = ee[(size_t)e0 * 64 + l];
    float ev1 = ee[(size_t)e1 * 64 + l];
    float ev2 = ee[(size_t)e2 * 64 + l];
    float ev3 = ee[(size_t)e3 * 64 + l];
    float xa0 = x2[d0 * 128 + l], xb0 = x2[d0 * 128 + 64 + l];
    float xa1 = x2[d1 * 128 + l], xb1 = x2[d1 * 128 + 64 + l];
    float xa2 = x2[d2 * 128 + l], xb2 = x2[d2 * 128 + 64 + l];
    float xa3 = x2[d3 * 128 + l], xb3 = x2[d3 * 128 + 64 + l];
    rsum += (w0 + w1) + (w2 + w3);
    s1 += w0 * ev0 + w1 * ev1 + w2 * ev2 + w3 * ev3;
    s2a += w0 * xa0 + w1 * xa1 + w2 * xa2 + w3 * xa3;
    s2b += w0 * xb0 + w1 * xb1 + w2 * xb2 + w3 * xb3;
  }
  for (; p < end; ++p) {
    int e0 = eidx[p];
    float w0 = wbuf[e0];
    int d0 = edge_dst[e0];
    rsum += w0;
    s1 += w0 * ee[(size_t)e0 * 64 + l];
    s2a += w0 * x2[d0 * 128 + l];
    s2b += w0 * x2[d0 * 128 + 64 + l];
  }
  float scale = (end > start) ? 1.0f / rsum : 0.f;
  sbuf1[(size_t)wid * 192 + l] = s2a * scale;
  sbuf1[(size_t)wid * 192 + 64 + l] = s2b * scale;
  sbuf1[(size_t)wid * 192 + 128 + l] = s1 * scale;
  if (l == 0) rs1[wid] = (end > start) ? rsum : 0.f;
}

// ---------------- dst finalize: merge 8 replicas, normalize ----------------
__global__ __launch_bounds__(256) void k_dst_final(const float* __restrict__ gee,
                                                   const float* __restrict__ gx1,
                                                   const float* __restrict__ rs2rep,
                                                   float* __restrict__ sbuf2,
                                                   float* __restrict__ rs2) {
  int t = blockIdx.x, tid = threadIdx.x;
  __shared__ float srt;
  if (tid == 0) {
    float r = 0.f;
    for (int rp = 0; rp < 8; ++rp) r += rs2rep[rp * 512 + t];
    srt = r; rs2[t] = r;
  }
  __syncthreads();
  float rtot = srt;
  float scale = rtot > 0.f ? 1.0f / rtot : 0.f;
  if (tid < 128) {
    float s = 0.f;
    for (int rp = 0; rp < 8; ++rp) s += gx1[(size_t)rp * 512 * 128 + t * 128 + tid];
    sbuf2[t * 192 + tid] = s * scale;
  } else if (tid < 192) {
    int k = tid - 128;
    float s = 0.f;
    for (int rp = 0; rp < 8; ++rp) s += gee[(size_t)rp * 512 * 64 + t * 64 + k];
    sbuf2[t * 192 + tid] = s * scale;
  }
}

// ---------------- fused output GEMM: out = mask * elu(A[M,320] @ a^T) ----------------
// mode 0 (entity): cols [0,128)=X row, [128,320)=S row (192 wide)
// mode 1 (type):   cols [0,128)=S[0..128), [128,256)=X row, [256,320)=S[128..192)
__global__ __launch_bounds__(256) void k_gemm(const float* __restrict__ X,
                                              const float* __restrict__ S,
                                              const float* __restrict__ aT,
                                              const float* __restrict__ rs,
                                              float* __restrict__ out,
                                              int M, int mode) {
  __shared__ float As[128][33];
  __shared__ float Bs[32][128];
  int tid = threadIdx.x;
  int row0 = blockIdx.x * 128;
  int tm = (tid >> 4) << 3;
  int tn = (tid & 15) << 3;
  float acc[8][8];
#pragma unroll
  for (int r = 0; r < 8; ++r)
#pragma unroll
    for (int cc = 0; cc < 8; ++cc) acc[r][cc] = 0.f;

  for (int k0 = 0; k0 < 320; k0 += 32) {
    const float4* bsrc = (const float4*)(aT + k0 * 128);
    float4* bdst = (float4*)(&Bs[0][0]);
#pragma unroll
    for (int q = 0; q < 4; ++q) bdst[tid + 256 * q] = bsrc[tid + 256 * q];
#pragma unroll
    for (int q = 0; q < 4; ++q) {
      int t0 = tid + 256 * q;
      int m = t0 >> 3;
      int kq = (t0 & 7) << 2;
      int gi = row0 + m;
      int p = k0 + kq;
      float4 v = make_float4(0.f, 0.f, 0.f, 0.f);
      if (gi < M) {
        const float* sp;
        if (mode == 0) sp = (p < 128) ? (X + (size_t)gi * 128 + p) : (S + (size_t)gi * 192 + (p - 128));
        else sp = (p >= 128 && p < 256) ? (X + (size_t)gi * 128 + (p - 128))
                                        : (S + (size_t)gi * 192 + (p < 128 ? p : p - 128));
        v = *(const float4*)sp;
      }
      As[m][kq + 0] = v.x; As[m][kq + 1] = v.y; As[m][kq + 2] = v.z; As[m][kq + 3] = v.w;
    }
    __syncthreads();
#pragma unroll
    for (int kk = 0; kk < 32; ++kk) {
      float af[8];
#pragma unroll
      for (int r = 0; r < 8; ++r) af[r] = As[tm + r][kk];
      float4 b0 = *(const float4*)&Bs[kk][tn];
      float4 b1 = *(const float4*)&Bs[kk][tn + 4];
      float bf[8] = {b0.x, b0.y, b0.z, b0.w, b1.x, b1.y, b1.z, b1.w};
#pragma unroll
      for (int r = 0; r < 8; ++r)
#pragma unroll
        for (int cc = 0; cc < 8; ++cc) acc[r][cc] += af[r] * bf[cc];
    }
    __syncthreads();
  }
#pragma unroll
  for (int r = 0; r < 8; ++r) {
    int gi = row0 + tm + r;
    if (gi < M) {
      float rsv = rs[gi];
      bool ok = rsv > 0.f;
      float4 o0, o1;
      float h;
      h = acc[r][0]; o0.x = ok ? (h > 0.f ? h : expm1f(h)) : 0.f;
      h = acc[r][1]; o0.y = ok ? (h > 0.f ? h : expm1f(h)) : 0.f;
      h = acc[r][2]; o0.z = ok ? (h > 0.f ? h : expm1f(h)) : 0.f;
      h = acc[r][3]; o0.w = ok ? (h > 0.f ? h : expm1f(h)) : 0.f;
      h = acc[r][4]; o1.x = ok ? (h > 0.f ? h : expm1f(h)) : 0.f;
      h = acc[r][5]; o1.y = ok ? (h > 0.f ? h : expm1f(h)) : 0.f;
      h = acc[r][6]; o1.z = ok ? (h > 0.f ? h : expm1f(h)) : 0.f;
      h = acc[r][7]; o1.w = ok ? (h > 0.f ? h : expm1f(h)) : 0.f;
      *(float4*)(out + (size_t)gi * 128 + tn) = o0;
      *(float4*)(out + (size_t)gi * 128 + tn + 4) = o1;
    }
  }
}

// =====================================================================================

static inline size_t align_up(size_t x, size_t a) { return (x + a - 1) & ~(a - 1); }

extern "C" void kernel_launch(void* const* d_in, const int* in_sizes, int n_in,
                              void* d_out, int out_size, void* d_ws, size_t ws_size,
                              hipStream_t stream) {
  const float* x1 = (const float*)d_in[0];
  const float* x2 = (const float*)d_in[1];
  const float* ee = (const float*)d_in[2];
  const float* a = (const float*)d_in[3];
  const float* a2 = (const float*)d_in[4];
  const int* esrc = (const int*)d_in[5];
  const int* edst = (const int*)d_in[6];
  float* out = (float*)d_out;

  char* base = (char*)d_ws;
  size_t off = 0;
  auto alloc = [&](size_t bytes) -> char* {
    char* p = base + off;
    off = align_up(off + bytes, 256);
    return p;
  };
  float* c = (float*)alloc(320 * 4);
  float* z2g = (float*)alloc(512 * 4);
  float* z1g = (float*)alloc(N1V * 4);
  float* aT = (float*)alloc(320 * 128 * 4);
  int* rp1 = (int*)alloc((N1V + 1) * 4);
  int* cur1 = (int*)alloc(N1V * 4);
  int* partials = (int*)alloc(64 * 4);
  int* eidx1 = (int*)alloc(NEV * 4);
  float* wbuf = (float*)alloc(NEV * 4);
  float* rs1 = (float*)alloc(N1V * 4);
  float* rs2 = (float*)alloc(512 * 4);
  float* gee = (float*)alloc((size_t)8 * 512 * 64 * 4);    // 1 MB
  float* gx1 = (float*)alloc((size_t)8 * 512 * 128 * 4);   // 2 MB
  float* rs2rep = (float*)alloc(8 * 512 * 4);
  float* sbuf1 = (float*)alloc((size_t)N1V * 192 * 4);
  float* sbuf2 = (float*)alloc(512 * 192 * 4);
  (void)ws_size; (void)out_size; (void)n_in; (void)in_sizes;

  hipMemsetAsync(cur1, 0, N1V * 4, stream);
  hipMemsetAsync(gee, 0, (size_t)8 * 512 * 64 * 4, stream);
  hipMemsetAsync(gx1, 0, (size_t)8 * 512 * 128 * 4, stream);
  hipMemsetAsync(rs2rep, 0, 8 * 512 * 4, stream);

  hipLaunchKernelGGL(k_prep, dim3(162), dim3(256), 0, stream, a, a2, c, aT);
  hipLaunchKernelGGL(k_z2, dim3(125), dim3(256), 0, stream, x2, c, z2g);
  hipLaunchKernelGGL(k_z1, dim3(25000), dim3(256), 0, stream, x1, c, z1g);
  hipLaunchKernelGGL(k_hist, dim3(1024), dim3(256), 0, stream, esrc, cur1);

  const int nScanBlocks = (N1V + 2047) / 2048;  // 49
  hipLaunchKernelGGL(k_scanA, dim3(nScanBlocks), dim3(256), 0, stream, cur1, rp1, partials, N1V);
  hipLaunchKernelGGL(k_scanP, dim3(1), dim3(64), 0, stream, partials, nScanBlocks);
  hipLaunchKernelGGL(k_scanC, dim3((N1V + 255) / 256), dim3(256), 0, stream, rp1, cur1, partials, N1V, NEV);
  hipLaunchKernelGGL(k_scatter, dim3(1024), dim3(256), 0, stream, esrc, cur1, eidx1);

  hipLaunchKernelGGL(k_edge, dim3(EGB), dim3(256), 0, stream,
                     ee, esrc, edst, x1, z1g, z2g, c, wbuf, gee, gx1, rs2rep);

  hipLaunchKernelGGL(k_src, dim3(N1V / 4), dim3(256), 0, stream,
                     x2, ee, edst, rp1, eidx1, wbuf, sbuf1, rs1);
  hipLaunchKernelGGL(k_dst_final, dim3(N2V), dim3(256), 0, stream,
                     gee, gx1, rs2rep, sbuf2, rs2);

  hipLaunchKernelGGL(k_gemm, dim3((N1V + 127) / 128), dim3(256), 0, stream,
                     x1, sbuf1, aT, rs1, out, N1V, 0);
  hipLaunchKernelGGL(k_gemm, dim3((N2V + 127) / 128), dim3(256), 0, stream,
                     x2, sbuf2, aT, rs2, out + (size_t)N1V * 128, N2V, 1);
}

// Round 5
// 732.710 us; speedup vs baseline: 1.7555x; 1.7555x over previous
//
#include <hip/hip_runtime.h>

#define N1V 100000
#define N2V 500
#define NEV 1000000
#define ALPHAV 0.2f
#define NB 256        // histogram/scatter blocks
#define CHUNK 3907    // ceil(NEV/NB)
#define CH 4          // dst chunks per type

__device__ __forceinline__ float wave_sum(float v) {
#pragma unroll
  for (int off = 32; off > 0; off >>= 1) v += __shfl_xor(v, off, 64);
  return v;
}

// ---------------- prep: c[320] = a^T @ a_2 ; aT[p*128+j] = a[j*320+p] ----------------
__global__ __launch_bounds__(256) void k_prep(const float* __restrict__ a,
                                              const float* __restrict__ a2,
                                              float* __restrict__ c,
                                              float* __restrict__ aT) {
  int b = blockIdx.x;
  if (b < 160) {
    int id = b * 256 + threadIdx.x;          // 0..40959
    int p = id >> 7, j = id & 127;
    aT[id] = a[j * 320 + p];
  } else {
    int p = (b - 160) * 256 + threadIdx.x;   // 0..511
    if (p < 320) {
      float s = 0.f;
      for (int k = 0; k < 128; ++k) s += a2[k] * a[k * 320 + p];
      c[p] = s;
    }
  }
}

// ---------------- z1[i] = x1[i].c1 ----------------
__global__ __launch_bounds__(256) void k_z1(const float* __restrict__ x1,
                                            const float* __restrict__ c,
                                            float* __restrict__ z1g) {
  int w = (blockIdx.x * 256 + threadIdx.x) >> 6;
  int l = threadIdx.x & 63;
  if (w >= N1V) return;
  float p = x1[(size_t)w * 128 + l] * c[l] + x1[(size_t)w * 128 + 64 + l] * c[64 + l];
  float s = wave_sum(p);
  if (l == 0) z1g[w] = s;
}

// ---------------- histogram: global atomics for src (100K buckets), LDS for dst ----------------
__global__ __launch_bounds__(256) void k_hist(const int* __restrict__ src,
                                              const int* __restrict__ dst,
                                              int* __restrict__ c1,
                                              int* __restrict__ hblk) {
  __shared__ int h[512];
  for (int i = threadIdx.x; i < 512; i += 256) h[i] = 0;
  __syncthreads();
  int b = blockIdx.x;
  int b0 = b * CHUNK, b1 = min(b0 + CHUNK, NEV);
  for (int e = b0 + threadIdx.x; e < b1; e += 256) {
    atomicAdd(&c1[src[e]], 1);
    atomicAdd(&h[dst[e]], 1);
  }
  __syncthreads();
  for (int i = threadIdx.x; i < 512; i += 256) hblk[b * 512 + i] = h[i];
}

// ---------------- column scan: hblk[b][t] -> exclusive prefix over b; tot2[t] ----------------
__global__ __launch_bounds__(256) void k_colscan(int* __restrict__ hblk,
                                                 int* __restrict__ tot2) {
  __shared__ int s[256];
  int t = blockIdx.x;            // 0..511
  int b = threadIdx.x;           // 0..255
  int v = hblk[b * 512 + t];
  s[b] = v; __syncthreads();
  for (int off = 1; off < 256; off <<= 1) {
    int tv = (b >= off) ? s[b - off] : 0;
    __syncthreads();
    if (b >= off) s[b] += tv;
    __syncthreads();
  }
  hblk[b * 512 + t] = s[b] - v;      // exclusive over blocks
  if (b == 255) tot2[t] = s[255];
}

// ---------------- scan for src counts ----------------
__global__ __launch_bounds__(256) void k_scanA(const int* __restrict__ cnt,
                                               int* __restrict__ outp,
                                               int* __restrict__ partials, int n) {
  __shared__ int s[256];
  int tid = threadIdx.x;
  int base = blockIdx.x * 2048 + tid * 8;
  int v[8]; int tot = 0;
#pragma unroll
  for (int j = 0; j < 8; ++j) { int idx = base + j; v[j] = (idx < n) ? cnt[idx] : 0; tot += v[j]; }
  s[tid] = tot; __syncthreads();
  for (int off = 1; off < 256; off <<= 1) {
    int tv = 0;
    if (tid >= off) tv = s[tid - off];
    __syncthreads();
    if (tid >= off) s[tid] += tv;
    __syncthreads();
  }
  int run = s[tid] - tot;
#pragma unroll
  for (int j = 0; j < 8; ++j) { int idx = base + j; if (idx < n) outp[idx] = run; run += v[j]; }
  if (tid == 255) partials[blockIdx.x] = s[255];
}

__global__ __launch_bounds__(512) void k_scanB(int* __restrict__ partials, int nPart,
                                               const int* __restrict__ tot2,
                                               int* __restrict__ rp2) {
  __shared__ int s[512];
  int tid = threadIdx.x;
  int v = (tid < N2V) ? tot2[tid] : 0;
  s[tid] = v; __syncthreads();
  for (int off = 1; off < 512; off <<= 1) {
    int tv = 0;
    if (tid >= off) tv = s[tid - off];
    __syncthreads();
    if (tid >= off) s[tid] += tv;
    __syncthreads();
  }
  if (tid < N2V) rp2[tid] = s[tid] - v;
  if (tid == N2V - 1) rp2[N2V] = s[tid];
  if (tid == 0) {
    int run = 0;
    for (int b = 0; b < nPart; ++b) { int t = partials[b]; partials[b] = run; run += t; }
  }
}

__global__ __launch_bounds__(256) void k_scanC(int* __restrict__ rp, int* __restrict__ cur,
                                               const int* __restrict__ partials, int n, int total) {
  int i = blockIdx.x * 256 + threadIdx.x;
  if (i < n) {
    int v = rp[i] + partials[i >> 11];
    rp[i] = v; cur[i] = v;
  }
  if (i == 0) rp[n] = total;
}

// ---------------- scatter into CSR: dst side atomic-free via precomputed block bases ----------------
__global__ __launch_bounds__(256) void k_scatter(const int* __restrict__ src,
                                                 const int* __restrict__ dst,
                                                 int* __restrict__ cur1,
                                                 const int* __restrict__ hblk,
                                                 const int* __restrict__ rp2,
                                                 int* __restrict__ e1, int* __restrict__ e2) {
  __shared__ int h[512];
  __shared__ int basep[512];
  int b = blockIdx.x;
  int b0 = b * CHUNK, b1 = min(b0 + CHUNK, NEV);
  for (int i = threadIdx.x; i < 512; i += 256) {
    basep[i] = ((i < N2V) ? rp2[i] : 0) + hblk[b * 512 + i];
    h[i] = 0;
  }
  __syncthreads();
  for (int e = b0 + threadIdx.x; e < b1; e += 256) {
    int sv = src[e], d = dst[e];
    int p = atomicAdd(&cur1[sv], 1);
    e1[p] = e;
    int loc = atomicAdd(&h[d], 1);
    e2[basep[d] + loc] = e;
  }
}

// ---------------- dst-grouped pass: computes w AND all dst-side sums ----------------
// block = (type t, chunk); 4 waves; wave-uniform edge per iter, unroll x2.
// writes wd[e] = (w, dst-bits); accumulates {w*x1[src] (128), w*ee (64), w (1)} -> acc2 atomics.
__global__ __launch_bounds__(256) void k_dst(const float* __restrict__ x1,
                                             const float* __restrict__ x2,
                                             const float* __restrict__ ee,
                                             const int* __restrict__ edge_src,
                                             const float* __restrict__ z1g,
                                             const float* __restrict__ c,
                                             const int* __restrict__ rp2,
                                             const int* __restrict__ eidx2,
                                             float2* __restrict__ wd,
                                             float* __restrict__ acc2) {
  __shared__ float red[4][224];
  int t = blockIdx.x / CH;
  int chunk = blockIdx.x % CH;
  int tid = threadIdx.x, wv = tid >> 6, l = tid & 63;
  float c3l = c[256 + l];
  // per-wave redundant z2[t] (block-constant)
  float z2t = wave_sum(x2[(size_t)t * 128 + l] * c[128 + l] +
                       x2[(size_t)t * 128 + 64 + l] * c[192 + l]);
  int start = rp2[t], end = rp2[t + 1];
  float sxa = 0.f, sxb = 0.f, s3 = 0.f, rsum = 0.f;
  int p = start + chunk * 4 + wv;
  for (; p + 16 < end; p += 32) {
    int e0 = eidx2[p], e1 = eidx2[p + 16];
    float ev0 = ee[(size_t)e0 * 64 + l];
    float ev1 = ee[(size_t)e1 * 64 + l];
    int s0 = edge_src[e0], s1i = edge_src[e1];
    float z1a = z1g[s0], z1b = z1g[s1i];
    float xa0 = x1[(size_t)s0 * 128 + l], xb0 = x1[(size_t)s0 * 128 + 64 + l];
    float xa1 = x1[(size_t)s1i * 128 + l], xb1 = x1[(size_t)s1i * 128 + 64 + l];
    float z30 = wave_sum(ev0 * c3l);
    float z31 = wave_sum(ev1 * c3l);
    float za = z1a + z2t + z30;
    float zb = z1b + z2t + z31;
    float zpa = za > 0.f ? za : ALPHAV * za;
    float zpb = zb > 0.f ? zb : ALPHAV * zb;
    float w0 = __expf(-zpa);
    float w1 = __expf(-zpb);
    if (l == 0) {
      wd[e0] = make_float2(w0, __int_as_float(t));
      wd[e1] = make_float2(w1, __int_as_float(t));
    }
    rsum += w0 + w1;
    s3 += w0 * ev0 + w1 * ev1;
    sxa += w0 * xa0 + w1 * xa1;
    sxb += w0 * xb0 + w1 * xb1;
  }
  for (; p < end; p += 16) {
    int e0 = eidx2[p];
    float ev0 = ee[(size_t)e0 * 64 + l];
    int s0 = edge_src[e0];
    float z1a = z1g[s0];
    float xa0 = x1[(size_t)s0 * 128 + l], xb0 = x1[(size_t)s0 * 128 + 64 + l];
    float z30 = wave_sum(ev0 * c3l);
    float za = z1a + z2t + z30;
    float zpa = za > 0.f ? za : ALPHAV * za;
    float w0 = __expf(-zpa);
    if (l == 0) wd[e0] = make_float2(w0, __int_as_float(t));
    rsum += w0;
    s3 += w0 * ev0;
    sxa += w0 * xa0;
    sxb += w0 * xb0;
  }
  red[wv][l] = sxa; red[wv][64 + l] = sxb; red[wv][128 + l] = s3;
  if (l == 0) red[wv][192] = rsum;
  __syncthreads();
  if (tid < 193) {
    float v = red[0][tid] + red[1][tid] + red[2][tid] + red[3][tid];
    if (v != 0.f) atomicAdd(&acc2[t * 256 + tid], v);
  }
}

// ---------------- dst finalize ----------------
__global__ __launch_bounds__(256) void k_dst_final(const float* __restrict__ acc2,
                                                   float* __restrict__ sbuf2,
                                                   float* __restrict__ rs2) {
  int t = blockIdx.x, tid = threadIdx.x;
  float rtot = acc2[t * 256 + 192];
  float scale = rtot > 0.f ? 1.0f / rtot : 0.f;
  if (tid < 192) sbuf2[t * 192 + tid] = acc2[t * 256 + tid] * scale;
  if (tid == 192) rs2[t] = rtot;
}

// ---------------- src gather pass: 4-wide pipelined gather+FMA (no shfl/exp) ----------------
__global__ __launch_bounds__(256) void k_src(const float* __restrict__ x2,
                                             const float* __restrict__ ee,
                                             const int* __restrict__ rp1,
                                             const int* __restrict__ eidx,
                                             const float2* __restrict__ wd,
                                             float* __restrict__ sbuf1,
                                             float* __restrict__ rs1) {
  int wid = (blockIdx.x * 256 + threadIdx.x) >> 6;
  int l = threadIdx.x & 63;
  if (wid >= N1V) return;
  int start = rp1[wid], end = rp1[wid + 1];
  float s2a = 0.f, s2b = 0.f, s1 = 0.f, rsum = 0.f;
  int p = start;
  for (; p + 4 <= end; p += 4) {
    int e0 = eidx[p], e1 = eidx[p + 1], e2 = eidx[p + 2], e3 = eidx[p + 3];
    float2 wd0 = wd[e0], wd1 = wd[e1], wd2 = wd[e2], wd3 = wd[e3];
    float ev0 = ee[(size_t)e0 * 64 + l];
    float ev1 = ee[(size_t)e1 * 64 + l];
    float ev2 = ee[(size_t)e2 * 64 + l];
    float ev3 = ee[(size_t)e3 * 64 + l];
    int d0 = __float_as_int(wd0.y), d1 = __float_as_int(wd1.y);
    int d2 = __float_as_int(wd2.y), d3 = __float_as_int(wd3.y);
    float w0 = wd0.x, w1 = wd1.x, w2 = wd2.x, w3 = wd3.x;
    float xa0 = x2[(size_t)d0 * 128 + l], xb0 = x2[(size_t)d0 * 128 + 64 + l];
    float xa1 = x2[(size_t)d1 * 128 + l], xb1 = x2[(size_t)d1 * 128 + 64 + l];
    float xa2 = x2[(size_t)d2 * 128 + l], xb2 = x2[(size_t)d2 * 128 + 64 + l];
    float xa3 = x2[(size_t)d3 * 128 + l], xb3 = x2[(size_t)d3 * 128 + 64 + l];
    rsum += (w0 + w1) + (w2 + w3);
    s1 += w0 * ev0 + w1 * ev1 + w2 * ev2 + w3 * ev3;
    s2a += w0 * xa0 + w1 * xa1 + w2 * xa2 + w3 * xa3;
    s2b += w0 * xb0 + w1 * xb1 + w2 * xb2 + w3 * xb3;
  }
  for (; p < end; ++p) {
    int e0 = eidx[p];
    float2 wd0 = wd[e0];
    float w0 = wd0.x;
    int d0 = __float_as_int(wd0.y);
    rsum += w0;
    s1 += w0 * ee[(size_t)e0 * 64 + l];
    s2a += w0 * x2[(size_t)d0 * 128 + l];
    s2b += w0 * x2[(size_t)d0 * 128 + 64 + l];
  }
  float scale = (end > start) ? 1.0f / rsum : 0.f;
  sbuf1[(size_t)wid * 192 + l] = s2a * scale;
  sbuf1[(size_t)wid * 192 + 64 + l] = s2b * scale;
  sbuf1[(size_t)wid * 192 + 128 + l] = s1 * scale;
  if (l == 0) rs1[wid] = (end > start) ? rsum : 0.f;
}

// ---------------- fused output GEMM: out = mask * elu(A[M,320] @ a^T) ----------------
// mode 0 (entity): cols [0,128)=X row, [128,320)=S row (192 wide)
// mode 1 (type):   cols [0,128)=S[0..128), [128,256)=X row, [256,320)=S[128..192)
__global__ __launch_bounds__(256) void k_gemm(const float* __restrict__ X,
                                              const float* __restrict__ S,
                                              const float* __restrict__ aT,
                                              const float* __restrict__ rs,
                                              float* __restrict__ out,
                                              int M, int mode) {
  __shared__ float As[128][33];
  __shared__ float Bs[32][128];
  int tid = threadIdx.x;
  int row0 = blockIdx.x * 128;
  int tm = (tid >> 4) << 3;
  int tn = (tid & 15) << 3;
  float acc[8][8];
#pragma unroll
  for (int r = 0; r < 8; ++r)
#pragma unroll
    for (int cc = 0; cc < 8; ++cc) acc[r][cc] = 0.f;

  for (int k0 = 0; k0 < 320; k0 += 32) {
    const float4* bsrc = (const float4*)(aT + k0 * 128);
    float4* bdst = (float4*)(&Bs[0][0]);
#pragma unroll
    for (int q = 0; q < 4; ++q) bdst[tid + 256 * q] = bsrc[tid + 256 * q];
#pragma unroll
    for (int q = 0; q < 4; ++q) {
      int t0 = tid + 256 * q;
      int m = t0 >> 3;
      int kq = (t0 & 7) << 2;
      int gi = row0 + m;
      int p = k0 + kq;
      float4 v = make_float4(0.f, 0.f, 0.f, 0.f);
      if (gi < M) {
        const float* sp;
        if (mode == 0) sp = (p < 128) ? (X + (size_t)gi * 128 + p) : (S + (size_t)gi * 192 + (p - 128));
        else sp = (p >= 128 && p < 256) ? (X + (size_t)gi * 128 + (p - 128))
                                        : (S + (size_t)gi * 192 + (p < 128 ? p : p - 128));
        v = *(const float4*)sp;
      }
      As[m][kq + 0] = v.x; As[m][kq + 1] = v.y; As[m][kq + 2] = v.z; As[m][kq + 3] = v.w;
    }
    __syncthreads();
#pragma unroll
    for (int kk = 0; kk < 32; ++kk) {
      float af[8];
#pragma unroll
      for (int r = 0; r < 8; ++r) af[r] = As[tm + r][kk];
      float4 b0 = *(const float4*)&Bs[kk][tn];
      float4 b1 = *(const float4*)&Bs[kk][tn + 4];
      float bf[8] = {b0.x, b0.y, b0.z, b0.w, b1.x, b1.y, b1.z, b1.w};
#pragma unroll
      for (int r = 0; r < 8; ++r)
#pragma unroll
        for (int cc = 0; cc < 8; ++cc) acc[r][cc] += af[r] * bf[cc];
    }
    __syncthreads();
  }
#pragma unroll
  for (int r = 0; r < 8; ++r) {
    int gi = row0 + tm + r;
    if (gi < M) {
      float rsv = rs[gi];
      bool ok = rsv > 0.f;
      float4 o0, o1;
      float h;
      h = acc[r][0]; o0.x = ok ? (h > 0.f ? h : expm1f(h)) : 0.f;
      h = acc[r][1]; o0.y = ok ? (h > 0.f ? h : expm1f(h)) : 0.f;
      h = acc[r][2]; o0.z = ok ? (h > 0.f ? h : expm1f(h)) : 0.f;
      h = acc[r][3]; o0.w = ok ? (h > 0.f ? h : expm1f(h)) : 0.f;
      h = acc[r][4]; o1.x = ok ? (h > 0.f ? h : expm1f(h)) : 0.f;
      h = acc[r][5]; o1.y = ok ? (h > 0.f ? h : expm1f(h)) : 0.f;
      h = acc[r][6]; o1.z = ok ? (h > 0.f ? h : expm1f(h)) : 0.f;
      h = acc[r][7]; o1.w = ok ? (h > 0.f ? h : expm1f(h)) : 0.f;
      *(float4*)(out + (size_t)gi * 128 + tn) = o0;
      *(float4*)(out + (size_t)gi * 128 + tn + 4) = o1;
    }
  }
}

// =====================================================================================

static inline size_t align_up(size_t x, size_t a) { return (x + a - 1) & ~(a - 1); }

extern "C" void kernel_launch(void* const* d_in, const int* in_sizes, int n_in,
                              void* d_out, int out_size, void* d_ws, size_t ws_size,
                              hipStream_t stream) {
  const float* x1 = (const float*)d_in[0];
  const float* x2 = (const float*)d_in[1];
  const float* ee = (const float*)d_in[2];
  const float* a = (const float*)d_in[3];
  const float* a2 = (const float*)d_in[4];
  const int* esrc = (const int*)d_in[5];
  const int* edst = (const int*)d_in[6];
  float* out = (float*)d_out;

  char* base = (char*)d_ws;
  size_t off = 0;
  auto alloc = [&](size_t bytes) -> char* {
    char* p = base + off;
    off = align_up(off + bytes, 256);
    return p;
  };
  float* c = (float*)alloc(320 * 4);
  float* z1g = (float*)alloc(N1V * 4);
  float* aT = (float*)alloc(320 * 128 * 4);
  int* rp1 = (int*)alloc((N1V + 1) * 4);
  int* cur1 = (int*)alloc(N1V * 4);
  int* rp2 = (int*)alloc(512 * 4);
  int* partials = (int*)alloc(64 * 4);
  int* hblk = (int*)alloc((size_t)NB * 512 * 4);
  int* tot2 = (int*)alloc(512 * 4);
  int* eidx1 = (int*)alloc(NEV * 4);
  int* eidx2 = (int*)alloc(NEV * 4);
  float2* wd = (float2*)alloc((size_t)NEV * 8);
  float* rs1 = (float*)alloc(N1V * 4);
  float* rs2 = (float*)alloc(512 * 4);
  float* sbuf1 = (float*)alloc((size_t)N1V * 192 * 4);
  float* sbuf2 = (float*)alloc(512 * 192 * 4);
  float* acc2 = (float*)alloc(512 * 256 * 4);
  (void)ws_size; (void)out_size; (void)n_in; (void)in_sizes;

  hipMemsetAsync(cur1, 0, N1V * 4, stream);
  hipMemsetAsync(acc2, 0, 512 * 256 * 4, stream);

  hipLaunchKernelGGL(k_prep, dim3(162), dim3(256), 0, stream, a, a2, c, aT);
  hipLaunchKernelGGL(k_z1, dim3(25000), dim3(256), 0, stream, x1, c, z1g);
  hipLaunchKernelGGL(k_hist, dim3(NB), dim3(256), 0, stream, esrc, edst, cur1, hblk);
  hipLaunchKernelGGL(k_colscan, dim3(512), dim3(256), 0, stream, hblk, tot2);

  const int nScanBlocks = (N1V + 2047) / 2048;  // 49
  hipLaunchKernelGGL(k_scanA, dim3(nScanBlocks), dim3(256), 0, stream, cur1, rp1, partials, N1V);
  hipLaunchKernelGGL(k_scanB, dim3(1), dim3(512), 0, stream, partials, nScanBlocks, tot2, rp2);
  hipLaunchKernelGGL(k_scanC, dim3((N1V + 255) / 256), dim3(256), 0, stream, rp1, cur1, partials, N1V, NEV);
  hipLaunchKernelGGL(k_scatter, dim3(NB), dim3(256), 0, stream, esrc, edst, cur1, hblk, rp2, eidx1, eidx2);

  hipLaunchKernelGGL(k_dst, dim3(N2V * CH), dim3(256), 0, stream,
                     x1, x2, ee, esrc, z1g, c, rp2, eidx2, wd, acc2);
  hipLaunchKernelGGL(k_dst_final, dim3(N2V), dim3(256), 0, stream, acc2, sbuf2, rs2);

  hipLaunchKernelGGL(k_src, dim3(N1V / 4), dim3(256), 0, stream,
                     x2, ee, rp1, eidx1, wd, sbuf1, rs1);

  hipLaunchKernelGGL(k_gemm, dim3((N1V + 127) / 128), dim3(256), 0, stream,
                     x1, sbuf1, aT, rs1, out, N1V, 0);
  hipLaunchKernelGGL(k_gemm, dim3((N2V + 127) / 128), dim3(256), 0, stream,
                     x2, sbuf2, aT, rs2, out + (size_t)N1V * 128, N2V, 1);
}

// Round 6
// 677.568 us; speedup vs baseline: 1.8983x; 1.0814x over previous
//
#include <hip/hip_runtime.h>

#define N1V 100000
#define N2V 500
#define NEV 1000000
#define ALPHAV 0.2f
#define NB 256        // histogram/scatter blocks
#define CHUNK 3907    // ceil(NEV/NB)
#define CH 4          // dst chunks per type
#define GP 132        // As padded stride (k-major)

__device__ __forceinline__ float wave_sum(float v) {
#pragma unroll
  for (int off = 32; off > 0; off >>= 1) v += __shfl_xor(v, off, 64);
  return v;
}

// ---------------- prep: c[320] = a^T @ a_2 ; aT[p*128+j] = a[j*320+p] ----------------
__global__ __launch_bounds__(256) void k_prep(const float* __restrict__ a,
                                              const float* __restrict__ a2,
                                              float* __restrict__ c,
                                              float* __restrict__ aT) {
  int b = blockIdx.x;
  if (b < 160) {
    int id = b * 256 + threadIdx.x;          // 0..40959
    int p = id >> 7, j = id & 127;
    aT[id] = a[j * 320 + p];
  } else {
    int p = (b - 160) * 256 + threadIdx.x;   // 0..511
    if (p < 320) {
      float s = 0.f;
      for (int k = 0; k < 128; ++k) s += a2[k] * a[k * 320 + p];
      c[p] = s;
    }
  }
}

// ---------------- z1[i] = x1[i].c1 ----------------
__global__ __launch_bounds__(256) void k_z1(const float* __restrict__ x1,
                                            const float* __restrict__ c,
                                            float* __restrict__ z1g) {
  int w = (blockIdx.x * 256 + threadIdx.x) >> 6;
  int l = threadIdx.x & 63;
  if (w >= N1V) return;
  float p = x1[(size_t)w * 128 + l] * c[l] + x1[(size_t)w * 128 + 64 + l] * c[64 + l];
  float s = wave_sum(p);
  if (l == 0) z1g[w] = s;
}

// ---------------- histogram: global atomics for src (100K buckets), LDS for dst ----------------
__global__ __launch_bounds__(256) void k_hist(const int* __restrict__ src,
                                              const int* __restrict__ dst,
                                              int* __restrict__ c1,
                                              int* __restrict__ hblk) {
  __shared__ int h[512];
  for (int i = threadIdx.x; i < 512; i += 256) h[i] = 0;
  __syncthreads();
  int b = blockIdx.x;
  int b0 = b * CHUNK, b1 = min(b0 + CHUNK, NEV);
  for (int e = b0 + threadIdx.x; e < b1; e += 256) {
    atomicAdd(&c1[src[e]], 1);
    atomicAdd(&h[dst[e]], 1);
  }
  __syncthreads();
  for (int i = threadIdx.x; i < 512; i += 256) hblk[b * 512 + i] = h[i];
}

// ---------------- column scan: hblk[b][t] -> exclusive prefix over b; tot2[t] ----------------
__global__ __launch_bounds__(256) void k_colscan(int* __restrict__ hblk,
                                                 int* __restrict__ tot2) {
  __shared__ int s[256];
  int t = blockIdx.x;            // 0..511
  int b = threadIdx.x;           // 0..255
  int v = hblk[b * 512 + t];
  s[b] = v; __syncthreads();
  for (int off = 1; off < 256; off <<= 1) {
    int tv = (b >= off) ? s[b - off] : 0;
    __syncthreads();
    if (b >= off) s[b] += tv;
    __syncthreads();
  }
  hblk[b * 512 + t] = s[b] - v;      // exclusive over blocks
  if (b == 255) tot2[t] = s[255];
}

// ---------------- scan for src counts ----------------
__global__ __launch_bounds__(256) void k_scanA(const int* __restrict__ cnt,
                                               int* __restrict__ outp,
                                               int* __restrict__ partials, int n) {
  __shared__ int s[256];
  int tid = threadIdx.x;
  int base = blockIdx.x * 2048 + tid * 8;
  int v[8]; int tot = 0;
#pragma unroll
  for (int j = 0; j < 8; ++j) { int idx = base + j; v[j] = (idx < n) ? cnt[idx] : 0; tot += v[j]; }
  s[tid] = tot; __syncthreads();
  for (int off = 1; off < 256; off <<= 1) {
    int tv = 0;
    if (tid >= off) tv = s[tid - off];
    __syncthreads();
    if (tid >= off) s[tid] += tv;
    __syncthreads();
  }
  int run = s[tid] - tot;
#pragma unroll
  for (int j = 0; j < 8; ++j) { int idx = base + j; if (idx < n) outp[idx] = run; run += v[j]; }
  if (tid == 255) partials[blockIdx.x] = s[255];
}

__global__ __launch_bounds__(512) void k_scanB(int* __restrict__ partials, int nPart,
                                               const int* __restrict__ tot2,
                                               int* __restrict__ rp2) {
  __shared__ int s[512];
  int tid = threadIdx.x;
  int v = (tid < N2V) ? tot2[tid] : 0;
  s[tid] = v; __syncthreads();
  for (int off = 1; off < 512; off <<= 1) {
    int tv = 0;
    if (tid >= off) tv = s[tid - off];
    __syncthreads();
    if (tid >= off) s[tid] += tv;
    __syncthreads();
  }
  if (tid < N2V) rp2[tid] = s[tid] - v;
  if (tid == N2V - 1) rp2[N2V] = s[tid];
  if (tid == 0) {
    int run = 0;
    for (int b = 0; b < nPart; ++b) { int t = partials[b]; partials[b] = run; run += t; }
  }
}

__global__ __launch_bounds__(256) void k_scanC(int* __restrict__ rp, int* __restrict__ cur,
                                               const int* __restrict__ partials, int n, int total) {
  int i = blockIdx.x * 256 + threadIdx.x;
  if (i < n) {
    int v = rp[i] + partials[i >> 11];
    rp[i] = v; cur[i] = v;
  }
  if (i == 0) rp[n] = total;
}

// ---------------- scatter into CSR: dst side atomic-free via precomputed block bases ----------------
__global__ __launch_bounds__(256) void k_scatter(const int* __restrict__ src,
                                                 const int* __restrict__ dst,
                                                 int* __restrict__ cur1,
                                                 const int* __restrict__ hblk,
                                                 const int* __restrict__ rp2,
                                                 int* __restrict__ e1, int* __restrict__ e2) {
  __shared__ int h[512];
  __shared__ int basep[512];
  int b = blockIdx.x;
  int b0 = b * CHUNK, b1 = min(b0 + CHUNK, NEV);
  for (int i = threadIdx.x; i < 512; i += 256) {
    basep[i] = ((i < N2V) ? rp2[i] : 0) + hblk[b * 512 + i];
    h[i] = 0;
  }
  __syncthreads();
  for (int e = b0 + threadIdx.x; e < b1; e += 256) {
    int sv = src[e], d = dst[e];
    int p = atomicAdd(&cur1[sv], 1);
    e1[p] = e;
    int loc = atomicAdd(&h[d], 1);
    e2[basep[d] + loc] = e;
  }
}

// ---------------- dst-grouped pass: computes w AND all dst-side sums ----------------
__global__ __launch_bounds__(256) void k_dst(const float* __restrict__ x1,
                                             const float* __restrict__ x2,
                                             const float* __restrict__ ee,
                                             const int* __restrict__ edge_src,
                                             const float* __restrict__ z1g,
                                             const float* __restrict__ c,
                                             const int* __restrict__ rp2,
                                             const int* __restrict__ eidx2,
                                             float2* __restrict__ wd,
                                             float* __restrict__ acc2) {
  __shared__ float red[4][224];
  int t = blockIdx.x / CH;
  int chunk = blockIdx.x % CH;
  int tid = threadIdx.x, wv = tid >> 6, l = tid & 63;
  float c3l = c[256 + l];
  float z2t = wave_sum(x2[(size_t)t * 128 + l] * c[128 + l] +
                       x2[(size_t)t * 128 + 64 + l] * c[192 + l]);
  int start = rp2[t], end = rp2[t + 1];
  float sxa = 0.f, sxb = 0.f, s3 = 0.f, rsum = 0.f;
  int p = start + chunk * 4 + wv;
  for (; p + 16 < end; p += 32) {
    int e0 = eidx2[p], e1 = eidx2[p + 16];
    float ev0 = ee[(size_t)e0 * 64 + l];
    float ev1 = ee[(size_t)e1 * 64 + l];
    int s0 = edge_src[e0], s1i = edge_src[e1];
    float z1a = z1g[s0], z1b = z1g[s1i];
    float xa0 = x1[(size_t)s0 * 128 + l], xb0 = x1[(size_t)s0 * 128 + 64 + l];
    float xa1 = x1[(size_t)s1i * 128 + l], xb1 = x1[(size_t)s1i * 128 + 64 + l];
    float z30 = wave_sum(ev0 * c3l);
    float z31 = wave_sum(ev1 * c3l);
    float za = z1a + z2t + z30;
    float zb = z1b + z2t + z31;
    float zpa = za > 0.f ? za : ALPHAV * za;
    float zpb = zb > 0.f ? zb : ALPHAV * zb;
    float w0 = __expf(-zpa);
    float w1 = __expf(-zpb);
    if (l == 0) {
      wd[e0] = make_float2(w0, __int_as_float(t));
      wd[e1] = make_float2(w1, __int_as_float(t));
    }
    rsum += w0 + w1;
    s3 += w0 * ev0 + w1 * ev1;
    sxa += w0 * xa0 + w1 * xa1;
    sxb += w0 * xb0 + w1 * xb1;
  }
  for (; p < end; p += 16) {
    int e0 = eidx2[p];
    float ev0 = ee[(size_t)e0 * 64 + l];
    int s0 = edge_src[e0];
    float z1a = z1g[s0];
    float xa0 = x1[(size_t)s0 * 128 + l], xb0 = x1[(size_t)s0 * 128 + 64 + l];
    float z30 = wave_sum(ev0 * c3l);
    float za = z1a + z2t + z30;
    float zpa = za > 0.f ? za : ALPHAV * za;
    float w0 = __expf(-zpa);
    if (l == 0) wd[e0] = make_float2(w0, __int_as_float(t));
    rsum += w0;
    s3 += w0 * ev0;
    sxa += w0 * xa0;
    sxb += w0 * xb0;
  }
  red[wv][l] = sxa; red[wv][64 + l] = sxb; red[wv][128 + l] = s3;
  if (l == 0) red[wv][192] = rsum;
  __syncthreads();
  if (tid < 193) {
    float v = red[0][tid] + red[1][tid] + red[2][tid] + red[3][tid];
    if (v != 0.f) atomicAdd(&acc2[t * 256 + tid], v);
  }
}

// ---------------- dst finalize ----------------
__global__ __launch_bounds__(256) void k_dst_final(const float* __restrict__ acc2,
                                                   float* __restrict__ sbuf2,
                                                   float* __restrict__ rs2) {
  int t = blockIdx.x, tid = threadIdx.x;
  float rtot = acc2[t * 256 + 192];
  float scale = rtot > 0.f ? 1.0f / rtot : 0.f;
  if (tid < 192) sbuf2[t * 192 + tid] = acc2[t * 256 + tid] * scale;
  if (tid == 192) rs2[t] = rtot;
}

// ---------------- src gather pass: 4-wide pipelined gather+FMA (no shfl/exp) ----------------
__global__ __launch_bounds__(256) void k_src(const float* __restrict__ x2,
                                             const float* __restrict__ ee,
                                             const int* __restrict__ rp1,
                                             const int* __restrict__ eidx,
                                             const float2* __restrict__ wd,
                                             float* __restrict__ sbuf1,
                                             float* __restrict__ rs1) {
  int wid = (blockIdx.x * 256 + threadIdx.x) >> 6;
  int l = threadIdx.x & 63;
  if (wid >= N1V) return;
  int start = rp1[wid], end = rp1[wid + 1];
  float s2a = 0.f, s2b = 0.f, s1 = 0.f, rsum = 0.f;
  int p = start;
  for (; p + 4 <= end; p += 4) {
    int e0 = eidx[p], e1 = eidx[p + 1], e2 = eidx[p + 2], e3 = eidx[p + 3];
    float2 wd0 = wd[e0], wd1 = wd[e1], wd2 = wd[e2], wd3 = wd[e3];
    float ev0 = ee[(size_t)e0 * 64 + l];
    float ev1 = ee[(size_t)e1 * 64 + l];
    float ev2 = ee[(size_t)e2 * 64 + l];
    float ev3 = ee[(size_t)e3 * 64 + l];
    int d0 = __float_as_int(wd0.y), d1 = __float_as_int(wd1.y);
    int d2 = __float_as_int(wd2.y), d3 = __float_as_int(wd3.y);
    float w0 = wd0.x, w1 = wd1.x, w2 = wd2.x, w3 = wd3.x;
    float xa0 = x2[(size_t)d0 * 128 + l], xb0 = x2[(size_t)d0 * 128 + 64 + l];
    float xa1 = x2[(size_t)d1 * 128 + l], xb1 = x2[(size_t)d1 * 128 + 64 + l];
    float xa2 = x2[(size_t)d2 * 128 + l], xb2 = x2[(size_t)d2 * 128 + 64 + l];
    float xa3 = x2[(size_t)d3 * 128 + l], xb3 = x2[(size_t)d3 * 128 + 64 + l];
    rsum += (w0 + w1) + (w2 + w3);
    s1 += w0 * ev0 + w1 * ev1 + w2 * ev2 + w3 * ev3;
    s2a += w0 * xa0 + w1 * xa1 + w2 * xa2 + w3 * xa3;
    s2b += w0 * xb0 + w1 * xb1 + w2 * xb2 + w3 * xb3;
  }
  for (; p < end; ++p) {
    int e0 = eidx[p];
    float2 wd0 = wd[e0];
    float w0 = wd0.x;
    int d0 = __float_as_int(wd0.y);
    rsum += w0;
    s1 += w0 * ee[(size_t)e0 * 64 + l];
    s2a += w0 * x2[(size_t)d0 * 128 + l];
    s2b += w0 * x2[(size_t)d0 * 128 + 64 + l];
  }
  float scale = (end > start) ? 1.0f / rsum : 0.f;
  sbuf1[(size_t)wid * 192 + l] = s2a * scale;
  sbuf1[(size_t)wid * 192 + 64 + l] = s2b * scale;
  sbuf1[(size_t)wid * 192 + 128 + l] = s1 * scale;
  if (l == 0) rs1[wid] = (end > start) ? rsum : 0.f;
}

// ---------------- fused output GEMM: out = mask * elu(A[M,320] @ a^T) ----------------
// k-major As (stride GP=132): thread reads its 8 A-rows as 2xfloat4.
// cols per thread: tn..tn+3 and 64+tn..64+tn+3, tn=(tid&15)*4 -> Bs reads span all banks.
__global__ __launch_bounds__(256, 4) void k_gemm(const float* __restrict__ X,
                                                 const float* __restrict__ S,
                                                 const float* __restrict__ aT,
                                                 const float* __restrict__ rs,
                                                 float* __restrict__ out,
                                                 int M, int mode) {
  __shared__ float As[32 * GP];
  __shared__ float Bs[32 * 128];
  int tid = threadIdx.x;
  int row0 = blockIdx.x * 128;
  int tm = (tid >> 4) << 3;     // 0,8,...,120
  int tn = (tid & 15) << 2;     // 0,4,...,60
  float acc[8][8];
#pragma unroll
  for (int r = 0; r < 8; ++r)
#pragma unroll
    for (int cc = 0; cc < 8; ++cc) acc[r][cc] = 0.f;

  for (int k0 = 0; k0 < 320; k0 += 32) {
    // stage B: contiguous 4096 floats of aT
    {
      const float4* bsrc = (const float4*)(aT + k0 * 128);
      float4* bdst = (float4*)Bs;
#pragma unroll
      for (int q = 0; q < 4; ++q) bdst[tid + 256 * q] = bsrc[tid + 256 * q];
    }
    // stage A (transposed to k-major)
#pragma unroll
    for (int q = 0; q < 4; ++q) {
      int t0 = tid + 256 * q;
      int m = t0 >> 3;
      int kq = (t0 & 7) << 2;
      int gi = row0 + m;
      int p = k0 + kq;
      float4 v = make_float4(0.f, 0.f, 0.f, 0.f);
      if (gi < M) {
        const float* sp;
        if (mode == 0) sp = (p < 128) ? (X + (size_t)gi * 128 + p) : (S + (size_t)gi * 192 + (p - 128));
        else sp = (p >= 128 && p < 256) ? (X + (size_t)gi * 128 + (p - 128))
                                        : (S + (size_t)gi * 192 + (p < 128 ? p : p - 128));
        v = *(const float4*)sp;
      }
      As[(kq + 0) * GP + m] = v.x;
      As[(kq + 1) * GP + m] = v.y;
      As[(kq + 2) * GP + m] = v.z;
      As[(kq + 3) * GP + m] = v.w;
    }
    __syncthreads();
#pragma unroll 8
    for (int kk = 0; kk < 32; ++kk) {
      float4 a0 = *(const float4*)&As[kk * GP + tm];
      float4 a1 = *(const float4*)&As[kk * GP + tm + 4];
      float4 b0 = *(const float4*)&Bs[kk * 128 + tn];
      float4 b1 = *(const float4*)&Bs[kk * 128 + 64 + tn];
      float af[8] = {a0.x, a0.y, a0.z, a0.w, a1.x, a1.y, a1.z, a1.w};
      float bf[8] = {b0.x, b0.y, b0.z, b0.w, b1.x, b1.y, b1.z, b1.w};
#pragma unroll
      for (int r = 0; r < 8; ++r)
#pragma unroll
        for (int cc = 0; cc < 8; ++cc) acc[r][cc] += af[r] * bf[cc];
    }
    __syncthreads();
  }
#pragma unroll
  for (int r = 0; r < 8; ++r) {
    int gi = row0 + tm + r;
    if (gi < M) {
      float rsv = rs[gi];
      bool ok = rsv > 0.f;
      float4 o0, o1;
      float h;
      h = acc[r][0]; o0.x = ok ? (h > 0.f ? h : expm1f(h)) : 0.f;
      h = acc[r][1]; o0.y = ok ? (h > 0.f ? h : expm1f(h)) : 0.f;
      h = acc[r][2]; o0.z = ok ? (h > 0.f ? h : expm1f(h)) : 0.f;
      h = acc[r][3]; o0.w = ok ? (h > 0.f ? h : expm1f(h)) : 0.f;
      h = acc[r][4]; o1.x = ok ? (h > 0.f ? h : expm1f(h)) : 0.f;
      h = acc[r][5]; o1.y = ok ? (h > 0.f ? h : expm1f(h)) : 0.f;
      h = acc[r][6]; o1.z = ok ? (h > 0.f ? h : expm1f(h)) : 0.f;
      h = acc[r][7]; o1.w = ok ? (h > 0.f ? h : expm1f(h)) : 0.f;
      *(float4*)(out + (size_t)gi * 128 + tn) = o0;
      *(float4*)(out + (size_t)gi * 128 + 64 + tn) = o1;
    }
  }
}

// =====================================================================================

static inline size_t align_up(size_t x, size_t a) { return (x + a - 1) & ~(a - 1); }

extern "C" void kernel_launch(void* const* d_in, const int* in_sizes, int n_in,
                              void* d_out, int out_size, void* d_ws, size_t ws_size,
                              hipStream_t stream) {
  const float* x1 = (const float*)d_in[0];
  const float* x2 = (const float*)d_in[1];
  const float* ee = (const float*)d_in[2];
  const float* a = (const float*)d_in[3];
  const float* a2 = (const float*)d_in[4];
  const int* esrc = (const int*)d_in[5];
  const int* edst = (const int*)d_in[6];
  float* out = (float*)d_out;

  char* base = (char*)d_ws;
  size_t off = 0;
  auto alloc = [&](size_t bytes) -> char* {
    char* p = base + off;
    off = align_up(off + bytes, 256);
    return p;
  };
  float* c = (float*)alloc(320 * 4);
  float* z1g = (float*)alloc(N1V * 4);
  float* aT = (float*)alloc(320 * 128 * 4);
  int* rp1 = (int*)alloc((N1V + 1) * 4);
  int* cur1 = (int*)alloc(N1V * 4);
  int* rp2 = (int*)alloc(512 * 4);
  int* partials = (int*)alloc(64 * 4);
  int* hblk = (int*)alloc((size_t)NB * 512 * 4);
  int* tot2 = (int*)alloc(512 * 4);
  int* eidx1 = (int*)alloc(NEV * 4);
  int* eidx2 = (int*)alloc(NEV * 4);
  float2* wd = (float2*)alloc((size_t)NEV * 8);
  float* rs1 = (float*)alloc(N1V * 4);
  float* rs2 = (float*)alloc(512 * 4);
  float* sbuf1 = (float*)alloc((size_t)N1V * 192 * 4);
  float* sbuf2 = (float*)alloc(512 * 192 * 4);
  float* acc2 = (float*)alloc(512 * 256 * 4);
  (void)ws_size; (void)out_size; (void)n_in; (void)in_sizes;

  hipMemsetAsync(cur1, 0, N1V * 4, stream);
  hipMemsetAsync(acc2, 0, 512 * 256 * 4, stream);

  hipLaunchKernelGGL(k_prep, dim3(162), dim3(256), 0, stream, a, a2, c, aT);
  hipLaunchKernelGGL(k_z1, dim3(25000), dim3(256), 0, stream, x1, c, z1g);
  hipLaunchKernelGGL(k_hist, dim3(NB), dim3(256), 0, stream, esrc, edst, cur1, hblk);
  hipLaunchKernelGGL(k_colscan, dim3(512), dim3(256), 0, stream, hblk, tot2);

  const int nScanBlocks = (N1V + 2047) / 2048;  // 49
  hipLaunchKernelGGL(k_scanA, dim3(nScanBlocks), dim3(256), 0, stream, cur1, rp1, partials, N1V);
  hipLaunchKernelGGL(k_scanB, dim3(1), dim3(512), 0, stream, partials, nScanBlocks, tot2, rp2);
  hipLaunchKernelGGL(k_scanC, dim3((N1V + 255) / 256), dim3(256), 0, stream, rp1, cur1, partials, N1V, NEV);
  hipLaunchKernelGGL(k_scatter, dim3(NB), dim3(256), 0, stream, esrc, edst, cur1, hblk, rp2, eidx1, eidx2);

  hipLaunchKernelGGL(k_dst, dim3(N2V * CH), dim3(256), 0, stream,
                     x1, x2, ee, esrc, z1g, c, rp2, eidx2, wd, acc2);
  hipLaunchKernelGGL(k_dst_final, dim3(N2V), dim3(256), 0, stream, acc2, sbuf2, rs2);

  hipLaunchKernelGGL(k_src, dim3(N1V / 4), dim3(256), 0, stream,
                     x2, ee, rp1, eidx1, wd, sbuf1, rs1);

  hipLaunchKernelGGL(k_gemm, dim3((N1V + 127) / 128), dim3(256), 0, stream,
                     x1, sbuf1, aT, rs1, out, N1V, 0);
  hipLaunchKernelGGL(k_gemm, dim3((N2V + 127) / 128), dim3(256), 0, stream,
                     x2, sbuf2, aT, rs2, out + (size_t)N1V * 128, N2V, 1);
}